// Round 18
// baseline (77.173 us; speedup 1.0000x reference)
//
#include <hip/hip_runtime.h>
#include <math.h>

// HSTU jagged attention, MFMA bf16, DMA-staged tile images, self-scheduled.
// out = (silu(Q K^T) / N * mask) V, no softmax. H=8, D=DV=64, N=1024.
// Mask (exact collapse): valid(n,m) = (m < thr(n)) | (m == n),
//   thr(n) = (an>0 ? an : M) + c - 1, an = clamp(n-c+1,0,M), M = L-c+1-ncand.
// R18: QT=128 per block (two 16-row q-halves per wave). kf read once -> both
// halves' QK; vf read once -> both halves' PV. LDS reads/q-row: 1.125->0.625
// b128; block-iters 12.3k->~7k. Items = 16 b x 8 h x 8 qt2 = 1024 = exactly
// one per block: schedule = parallel rank + direct decode. LDS 48KB -> 3
// blocks/CU, declared (256,3) for ~170-VGPR headroom (no R13-style spills).

#define HH      8
#define DDIM    64
#define QT2     128
#define KT      64
#define STRIDE  512
#define NMAX    1024
#define NORD    16
#define TILE_HW 8192          // ushorts per tile image (16 KB)
#define NBLK    1024

typedef __attribute__((ext_vector_type(8))) short short8;
typedef __attribute__((ext_vector_type(4))) float f32x4;
typedef __attribute__((ext_vector_type(4))) uint  u32x4;

static __device__ __forceinline__ uint pk2(float a, float b) {
  uint r;
  asm("v_cvt_pk_bf16_f32 %0, %1, %2" : "=v"(r) : "v"(a), "v"(b));
  return r;
}

static __device__ __forceinline__ void dma16(const ushort* g, ushort* l) {
  __builtin_amdgcn_global_load_lds(
      (const __attribute__((address_space(1))) void*)g,
      (__attribute__((address_space(3))) void*)l, 16, 0, 0);
}

// ---- pre-pass: packed swizzled tile images [K 8KB | (V/N)^T 8KB]. ----
__global__ void build_tiles(const float* __restrict__ tk,
                            const float* __restrict__ tv,
                            ushort* __restrict__ tiles,
                            const int* __restrict__ offsets,
                            const int* __restrict__ pN) {
  const int mt = blockIdx.x, h = blockIdx.y, b = blockIdx.z;
  const int off = offsets[b];
  const int L   = offsets[b + 1] - off;
  if (mt * 64 >= L) return;
  const int tid = threadIdx.x;
  const float invN = 1.0f / (float)pN[0];

  __shared__ ushort tr[64][66];

  ushort* img = tiles + (size_t)((b * NORD + mt) * HH + h) * TILE_HW;
  const int row = tid >> 2;
  const int c0  = (tid & 3) * 16;
  const int m   = mt * 64 + row;
  const int sw  = (row & 7) << 3;

  {
    uint u[8];
    if (m < L) {
      const float* s = tk + (size_t)(off + m) * STRIDE + h * DDIM + c0;
      float4 a = *(const float4*)(s),      b4 = *(const float4*)(s + 4);
      float4 c4 = *(const float4*)(s + 8), d4 = *(const float4*)(s + 12);
      u[0] = pk2(a.x, a.y);   u[1] = pk2(a.z, a.w);
      u[2] = pk2(b4.x, b4.y); u[3] = pk2(b4.z, b4.w);
      u[4] = pk2(c4.x, c4.y); u[5] = pk2(c4.z, c4.w);
      u[6] = pk2(d4.x, d4.y); u[7] = pk2(d4.z, d4.w);
    } else {
#pragma unroll
      for (int j = 0; j < 8; ++j) u[j] = 0u;
    }
    *(uint4*)&img[row * 64 + (c0 ^ sw)]       = make_uint4(u[0], u[1], u[2], u[3]);
    *(uint4*)&img[row * 64 + ((c0 + 8) ^ sw)] = make_uint4(u[4], u[5], u[6], u[7]);
  }
  {
    uint u[8];
    if (m < L) {
      const float* s = tv + (size_t)(off + m) * STRIDE + h * DDIM + c0;
      float4 a = *(const float4*)(s),      b4 = *(const float4*)(s + 4);
      float4 c4 = *(const float4*)(s + 8), d4 = *(const float4*)(s + 12);
      u[0] = pk2(a.x * invN, a.y * invN);   u[1] = pk2(a.z * invN, a.w * invN);
      u[2] = pk2(b4.x * invN, b4.y * invN); u[3] = pk2(b4.z * invN, b4.w * invN);
      u[4] = pk2(c4.x * invN, c4.y * invN); u[5] = pk2(c4.z * invN, c4.w * invN);
      u[6] = pk2(d4.x * invN, d4.y * invN); u[7] = pk2(d4.z * invN, d4.w * invN);
    } else {
#pragma unroll
      for (int j = 0; j < 8; ++j) u[j] = 0u;
    }
#pragma unroll
    for (int j = 0; j < 8; ++j) *(uint*)&tr[row][c0 + 2 * j] = u[j];
  }
  __syncthreads();
  {
    const int dv = tid >> 2;
    const int tc = (tid & 3) * 16;
    uint u[8];
#pragma unroll
    for (int j = 0; j < 8; ++j)
      u[j] = (uint)tr[tc + 2 * j][dv] | ((uint)tr[tc + 2 * j + 1][dv] << 16);
    *(uint4*)&img[4096 + row * 64 + (tc ^ sw)]       = make_uint4(u[0], u[1], u[2], u[3]);
    *(uint4*)&img[4096 + row * 64 + ((tc + 8) ^ sw)] = make_uint4(u[4], u[5], u[6], u[7]);
  }
}

__global__ void zero_ctr(uint* ctr) { *ctr = 0u; }

// ---- main: QT=128, one item per block, shared kf/vf across q-halves ----
__launch_bounds__(256, 3)
__global__ void hstu_s(const float* __restrict__ tq,
                       const ushort* __restrict__ tiles,
                       const int* __restrict__ offsets,
                       const int* __restrict__ ncand,
                       const int* __restrict__ nctx,
                       float* __restrict__ out, int Tm1, int Bb) {
  __shared__ ushort KV[2][TILE_HW];  // double-buffered [K 8KB | V^T 8KB]  32 KB
  __shared__ ushort Ps[8 * 1024];    // 2 halves x 4 waves P strips        16 KB

  const int tid  = threadIdx.x;
  const int w    = tid >> 6;
  const int lane = tid & 63;
  const int lo   = lane & 15;
  const int hi   = lane >> 4;

  // ---- schedule: parallel rank, direct decode (one item per block).
  // scr[0..15]=nq, scr[16..23]=gb0 per group, scr[24..31]=gb1
  int* scr = (int*)Ps;
  if (tid < 16)
    scr[tid] = (tid < Bb) ? (offsets[tid + 1] - offsets[tid] + 63) / 64 : 0;
  if (tid >= 16 && tid < 32) scr[tid] = -1;
  __syncthreads();
  if (tid < Bb) {
    const int nqb = scr[tid];
    int r = 0;
#pragma unroll
    for (int j = 0; j < 16; ++j) {
      int v = scr[j];
      r += (j < Bb) & ((v > nqb) | ((v == nqb) & (j < tid)));
    }
    if (r < Bb / 2) scr[16 + (r & 7)] = tid;
    else            scr[24 + ((Bb - 1 - r) & 7)] = tid;
  }
  __syncthreads();
  const int g     = blockIdx.x & 7;
  const int rest  = blockIdx.x >> 3;
  const int h     = rest >> 4;
  const int local = rest & 15;
  const int b     = scr[16 + (local & 8) + g];   // local<8 -> gb0, else gb1
  const int qt2   = local & 7;
  if (b < 0) return;
  const int nq  = scr[b];
  const int nq2 = (nq + 1) >> 1;
  if (qt2 >= nq2) return;
  // scr reads complete per-thread here; first P write is after the first
  // loop-top __syncthreads(), so the alias is safe.

  const int off = offsets[b];
  const int L   = offsets[b + 1] - off;
  const int n0  = qt2 * QT2;
  const int c   = nctx[b];
  const int M   = L - c + 1 - ncand[b];
  const int m_hi  = (n0 < c) ? L : min(n0 + QT2, L);
  const int niter = (m_hi + KT - 1) / KT;

  const ushort* ibase = tiles + (size_t)(b * NORD * HH + h) * TILE_HW;

  // prologue: DMA tile 0 into KV[0]
  {
    const ushort* src = ibase + w * 2048 + lane * 8;
    ushort* dst = &KV[0][w * 2048];
#pragma unroll
    for (int i = 0; i < 4; ++i) dma16(src + i * 512, dst + i * 512);
  }

  // Q -> registers, both halves (q-rows n0 + {0,64} + w*16 + lo)
  short8 qfA[2], qfB[2];
  {
    int qr = min(off + n0 + w * 16 + lo, Tm1);
    const float* qp = tq + (size_t)qr * STRIDE + h * DDIM + hi * 8;
    float4 qa = *(const float4*)(qp);
    float4 qb = *(const float4*)(qp + 4);
    float4 qc = *(const float4*)(qp + 32);
    float4 qd = *(const float4*)(qp + 36);
    u32x4 v0 = {pk2(qa.x, qa.y), pk2(qa.z, qa.w), pk2(qb.x, qb.y), pk2(qb.z, qb.w)};
    u32x4 v1 = {pk2(qc.x, qc.y), pk2(qc.z, qc.w), pk2(qd.x, qd.y), pk2(qd.z, qd.w)};
    qfA[0] = __builtin_bit_cast(short8, v0);
    qfA[1] = __builtin_bit_cast(short8, v1);
  }
  {
    int qr = min(off + n0 + 64 + w * 16 + lo, Tm1);
    const float* qp = tq + (size_t)qr * STRIDE + h * DDIM + hi * 8;
    float4 qa = *(const float4*)(qp);
    float4 qb = *(const float4*)(qp + 4);
    float4 qc = *(const float4*)(qp + 32);
    float4 qd = *(const float4*)(qp + 36);
    u32x4 v0 = {pk2(qa.x, qa.y), pk2(qa.z, qa.w), pk2(qb.x, qb.y), pk2(qb.z, qb.w)};
    u32x4 v1 = {pk2(qc.x, qc.y), pk2(qc.z, qc.w), pk2(qd.x, qd.y), pk2(qd.z, qd.w)};
    qfB[0] = __builtin_bit_cast(short8, v0);
    qfB[1] = __builtin_bit_cast(short8, v1);
  }

  // per-lane mask scalars for both halves
  const int  nA   = n0 + w * 16 + lo;
  const int  anA  = min(max(nA - c + 1, 0), M);
  const int  thrA = (anA > 0 ? anA : M) + c - 1;
  const bool nokA = nA < L;
  const int  nB   = nA + 64;
  const int  anB  = min(max(nB - c + 1, 0), M);
  const int  thrB = (anB > 0 ? anB : M) + c - 1;
  const bool nokB = nB < L;

  f32x4 oaccA[4], oaccB[4];
#pragma unroll
  for (int i = 0; i < 4; ++i) {
    oaccA[i] = (f32x4){0.f, 0.f, 0.f, 0.f};
    oaccB[i] = (f32x4){0.f, 0.f, 0.f, 0.f};
  }

  ushort* PwA = &Ps[w * 1024];
  ushort* PwB = &Ps[(w + 4) * 1024];

  for (int t = 0; t < niter; ++t) {
    __syncthreads();   // drains tile-t DMA; gates buf (t+1)&1 reuse

    if (t + 1 < niter) {
      const ushort* src = ibase + (size_t)(t + 1) * (HH * TILE_HW)
                          + w * 2048 + lane * 8;
      ushort* dst = &KV[(t + 1) & 1][w * 2048];
#pragma unroll
      for (int i = 0; i < 4; ++i) dma16(src + i * 512, dst + i * 512);
    }

    const ushort* Kb = KV[t & 1];
    const ushort* Vb = Kb + 4096;
    const int m0 = t * KT;

    // S^T = K Q^T for both halves; kf read ONCE
#pragma unroll
    for (int kc = 0; kc < 4; ++kc) {
      const int krw = kc * 16 + lo;
      const int ksw = (krw & 7) << 3;
      short8 kf0 = *(const short8*)&Kb[krw * 64 + ((hi * 8) ^ ksw)];
      short8 kf1 = *(const short8*)&Kb[krw * 64 + ((32 + hi * 8) ^ ksw)];
      f32x4 sa = (f32x4){0.f, 0.f, 0.f, 0.f};
      sa = __builtin_amdgcn_mfma_f32_16x16x32_bf16(kf0, qfA[0], sa, 0, 0, 0);
      sa = __builtin_amdgcn_mfma_f32_16x16x32_bf16(kf1, qfA[1], sa, 0, 0, 0);
      f32x4 sb = (f32x4){0.f, 0.f, 0.f, 0.f};
      sb = __builtin_amdgcn_mfma_f32_16x16x32_bf16(kf0, qfB[0], sb, 0, 0, 0);
      sb = __builtin_amdgcn_mfma_f32_16x16x32_bf16(kf1, qfB[1], sb, 0, 0, 0);
      const int mb = m0 + kc * 16 + 4 * hi;
      float ppa[4], ppb[4];
#pragma unroll
      for (int r = 0; r < 4; ++r) {
        const int mm = mb + r;
        const bool vA = nokA & ((mm < thrA) | (mm == nA));
        float sAv = vA ? sa[r] : 0.f;                 // silu(0)=0
        ppa[r] = sAv * __builtin_amdgcn_rcpf(1.f + __expf(-sAv));
        const bool vB = nokB & ((mm < thrB) | (mm == nB));
        float sBv = vB ? sb[r] : 0.f;
        ppb[r] = sBv * __builtin_amdgcn_rcpf(1.f + __expf(-sBv));
      }
      const int col = kc * 16 + 4 * hi;
      const int pso = lo * 64 + (col ^ ((lo & 7) << 3));
      *(uint2*)&PwA[pso] = make_uint2(pk2(ppa[0], ppa[1]), pk2(ppa[2], ppa[3]));
      *(uint2*)&PwB[pso] = make_uint2(pk2(ppb[0], ppb[1]), pk2(ppb[2], ppb[3]));
    }

    // O += P V for both halves; vf read ONCE (wave-private, no barrier)
#pragma unroll
    for (int mc = 0; mc < 2; ++mc) {
      const int pro = lo * 64 + ((mc * 32 + hi * 8) ^ ((lo & 7) << 3));
      short8 pfA = *(const short8*)&PwA[pro];
      short8 pfB = *(const short8*)&PwB[pro];
#pragma unroll
      for (int dvc = 0; dvc < 4; ++dvc) {
        const int vrow = dvc * 16 + lo;
        short8 vf = *(const short8*)&Vb[vrow * 64 + ((mc * 32 + hi * 8) ^ ((vrow & 7) << 3))];
        oaccA[dvc] = __builtin_amdgcn_mfma_f32_16x16x32_bf16(pfA, vf, oaccA[dvc], 0, 0, 0);
        oaccB[dvc] = __builtin_amdgcn_mfma_f32_16x16x32_bf16(pfB, vf, oaccB[dvc], 0, 0, 0);
      }
    }
  }

  // write out (fp32), C-frag layout, both halves
#pragma unroll
  for (int dvc = 0; dvc < 4; ++dvc) {
#pragma unroll
    for (int r = 0; r < 4; ++r) {
      int nn = n0 + w * 16 + hi * 4 + r;
      if (nn < L)
        out[(size_t)(off + nn) * STRIDE + h * DDIM + dvc * 16 + lo] = oaccA[dvc][r];
      int nn2 = nn + 64;
      if (nn2 < L)
        out[(size_t)(off + nn2) * STRIDE + h * DDIM + dvc * 16 + lo] = oaccB[dvc][r];
    }
  }
}

// ---- fallback (ws too small / B>16): reg-staged fp32 queue path (QT=64) ----
__launch_bounds__(256)
__global__ void hstu_fb(const float* __restrict__ tq,
                        const float* __restrict__ tk,
                        const float* __restrict__ tv,
                        const int* __restrict__ offsets,
                        const int* __restrict__ pN,
                        const int* __restrict__ ncand,
                        const int* __restrict__ nctx,
                        float* __restrict__ out,
                        uint* __restrict__ ctr,
                        int Tm1, int Bb) {
  const int bhc    = Bb * HH;
  const int nitems = NORD * bhc;

  __shared__ ushort Ks[KT * DDIM];
  __shared__ ushort Vt[DDIM * KT];
  __shared__ ushort Ps[4 * 1024];
  __shared__ int s_item;

  const int tid  = threadIdx.x;
  const int w    = tid >> 6;
  const int lane = tid & 63;
  const int lo   = lane & 15;
  const int hi   = lane >> 4;
  const float invN = 1.0f / (float)pN[0];
  ushort* Pw = &Ps[w * 1024];

  for (;;) {
    __syncthreads();
    if (tid == 0) s_item = (int)atomicAdd(ctr, 1u);
    __syncthreads();
    const int item = s_item;
    if (item >= nitems) return;
    const int ord = item / bhc;
    const int rem = item - ord * bhc;
    const int b = rem / HH, h = rem - b * HH;
    const int qt = (ord == 0) ? 0 : (NORD - ord);
    const int off = offsets[b];
    const int L   = offsets[b + 1] - off;
    const int n0  = qt * 64;
    if (n0 >= L) continue;

    const int c = nctx[b];
    const int M = L - c + 1 - ncand[b];
    const int m_hi  = (n0 < c) ? L : min(n0 + 64, L);
    const int niter = (m_hi + KT - 1) / KT;

    short8 qf[2];
    {
      int qr = min(off + n0 + w * 16 + lo, Tm1);
      const float* qp = tq + (size_t)qr * STRIDE + h * DDIM + hi * 8;
      float4 qa = *(const float4*)(qp);
      float4 qb = *(const float4*)(qp + 4);
      float4 qc = *(const float4*)(qp + 32);
      float4 qd = *(const float4*)(qp + 36);
      u32x4 v0 = {pk2(qa.x, qa.y), pk2(qa.z, qa.w), pk2(qb.x, qb.y), pk2(qb.z, qb.w)};
      u32x4 v1 = {pk2(qc.x, qc.y), pk2(qc.z, qc.w), pk2(qd.x, qd.y), pk2(qd.z, qd.w)};
      qf[0] = __builtin_bit_cast(short8, v0);
      qf[1] = __builtin_bit_cast(short8, v1);
    }

    const int  n   = n0 + w * 16 + lo;
    const int  an  = min(max(n - c + 1, 0), M);
    const int  thr = (an > 0 ? an : M) + c - 1;
    const bool nok = n < L;

    f32x4 oacc[4];
#pragma unroll
    for (int i = 0; i < 4; ++i) oacc[i] = (f32x4){0.f, 0.f, 0.f, 0.f};

    for (int t = 0; t < niter; ++t) {
      const int m0 = t * KT;
      __syncthreads();
#pragma unroll
      for (int jj = 0; jj < 4; ++jj) {
        int row = (tid >> 4) + jj * 16;
        int r2  = min(off + m0 + row, Tm1);
        float4 kv = *(const float4*)(tk + (size_t)r2 * STRIDE + h * DDIM + (tid & 15) * 4);
        uint2 pk;
        pk.x = pk2(kv.x, kv.y);
        pk.y = pk2(kv.z, kv.w);
        *(uint2*)&Ks[row * 64 + (((tid & 15) * 4) ^ ((row & 7) << 3))] = pk;
      }
      {
        uint bb[8];
#pragma unroll
        for (int j = 0; j < 8; ++j) {
          int ra = min(off + m0 + w * 16 + 2 * j,     Tm1);
          int rb = min(off + m0 + w * 16 + 2 * j + 1, Tm1);
          float va = tv[(size_t)ra * STRIDE + h * DDIM + lane];
          float vb = tv[(size_t)rb * STRIDE + h * DDIM + lane];
          bb[j] = pk2(va, vb);
        }
        int s = (lane & 7) << 3;
        *(uint4*)&Vt[lane * 64 + ((w * 16)     ^ s)] = make_uint4(bb[0], bb[1], bb[2], bb[3]);
        *(uint4*)&Vt[lane * 64 + ((w * 16 + 8) ^ s)] = make_uint4(bb[4], bb[5], bb[6], bb[7]);
      }
      __syncthreads();

#pragma unroll
      for (int kc = 0; kc < 4; ++kc) {
        const int krw = kc * 16 + lo;
        const int ksw = (krw & 7) << 3;
        short8 kf0 = *(const short8*)&Ks[krw * 64 + ((hi * 8) ^ ksw)];
        short8 kf1 = *(const short8*)&Ks[krw * 64 + ((32 + hi * 8) ^ ksw)];
        f32x4 s4 = (f32x4){0.f, 0.f, 0.f, 0.f};
        s4 = __builtin_amdgcn_mfma_f32_16x16x32_bf16(kf0, qf[0], s4, 0, 0, 0);
        s4 = __builtin_amdgcn_mfma_f32_16x16x32_bf16(kf1, qf[1], s4, 0, 0, 0);
        const int mb = m0 + kc * 16 + 4 * hi;
        float pp[4];
#pragma unroll
        for (int r = 0; r < 4; ++r) {
          const int mm = mb + r;
          const bool valid = nok & ((mm < thr) | (mm == n));
          float s = valid ? s4[r] : 0.f;
          pp[r] = s * invN * __builtin_amdgcn_rcpf(1.f + __expf(-s));
        }
        const int col = kc * 16 + 4 * hi;
        *(uint2*)&Pw[lo * 64 + (col ^ ((lo & 7) << 3))] =
            make_uint2(pk2(pp[0], pp[1]), pk2(pp[2], pp[3]));
      }

#pragma unroll
      for (int mc = 0; mc < 2; ++mc) {
        short8 pf = *(const short8*)&Pw[lo * 64 + ((mc * 32 + hi * 8) ^ ((lo & 7) << 3))];
#pragma unroll
        for (int dvc = 0; dvc < 4; ++dvc) {
          const int vrow = dvc * 16 + lo;
          short8 vf = *(const short8*)&Vt[vrow * 64 + ((mc * 32 + hi * 8) ^ ((vrow & 7) << 3))];
          oacc[dvc] = __builtin_amdgcn_mfma_f32_16x16x32_bf16(pf, vf, oacc[dvc], 0, 0, 0);
        }
      }
    }

#pragma unroll
    for (int dvc = 0; dvc < 4; ++dvc) {
#pragma unroll
      for (int r = 0; r < 4; ++r) {
        int nn = n0 + w * 16 + hi * 4 + r;
        if (nn < L)
          out[(size_t)(off + nn) * STRIDE + h * DDIM + dvc * 16 + lo] = oacc[dvc][r];
      }
    }
  }
}

extern "C" void kernel_launch(void* const* d_in, const int* in_sizes, int n_in,
                              void* d_out, int out_size, void* d_ws, size_t ws_size,
                              hipStream_t stream) {
  const float* tq      = (const float*)d_in[0];
  const float* tk      = (const float*)d_in[1];
  const float* tv      = (const float*)d_in[2];
  const int*   offsets = (const int*)d_in[3];
  const int*   pN      = (const int*)d_in[4];
  const int*   ncand   = (const int*)d_in[5];
  const int*   nctx    = (const int*)d_in[6];
  float*       out     = (float*)d_out;

  const int B = in_sizes[3] - 1;
  const int T = in_sizes[0] / STRIDE;

  uint*   ctr   = (uint*)d_ws;
  ushort* tiles = (ushort*)((char*)d_ws + 256);
  const size_t need = 256 + (size_t)B * NORD * HH * TILE_HW * sizeof(ushort);

  dim3 block(256);

  if (ws_size >= need && B <= 16) {
    dim3 tgrid(NORD, HH, B);
    build_tiles<<<tgrid, block, 0, stream>>>(tk, tv, tiles, offsets, pN);
    hstu_s<<<NBLK, block, 0, stream>>>(tq, tiles, offsets, ncand, nctx, out,
                                       T - 1, B);
  } else {
    zero_ctr<<<1, 1, 0, stream>>>(ctr);
    hstu_fb<<<NBLK, block, 0, stream>>>(tq, tk, tv, offsets, pN, ncand,
                                        nctx, out, ctr, T - 1, B);
  }
}

// Round 19
// 58.071 us; speedup vs baseline: 1.3289x; 1.3289x over previous
//
#include <hip/hip_runtime.h>
#include <math.h>

// HSTU jagged attention, MFMA bf16, DMA-staged tile images, self-scheduled.
// out = (silu(Q K^T) / N * mask) V, no softmax. H=8, D=DV=64, N=1024.
// Mask (exact collapse): valid(n,m) = (m < thr(n)) | (m == n),
//   thr(n) = (an>0 ? an : M) + c - 1, an = clamp(n-c+1,0,M), M = L-c+1-ncand.
// R19: revert to QT=64 (R18's QT=128 lost LPT pairing -> occupancy 15%).
// Two changes vs R17: (a) single-buffered KV (24KB LDS -> 6 blocks/CU,
// 24 waves: TLP hides DMA latency instead of dbuf ILP); (b) wave-uniform
// all-valid fast path for interior tiles (skip mask, ~80% of tiles).

#define HH      8
#define DDIM    64
#define QT      64
#define KT      64
#define STRIDE  512
#define NMAX    1024
#define NORD    16
#define TILE_HW 8192          // ushorts per tile image (16 KB)
#define NBLK    1024

typedef __attribute__((ext_vector_type(8))) short short8;
typedef __attribute__((ext_vector_type(4))) float f32x4;
typedef __attribute__((ext_vector_type(4))) uint  u32x4;

static __device__ __forceinline__ uint pk2(float a, float b) {
  uint r;
  asm("v_cvt_pk_bf16_f32 %0, %1, %2" : "=v"(r) : "v"(a), "v"(b));
  return r;
}

static __device__ __forceinline__ void dma16(const ushort* g, ushort* l) {
  __builtin_amdgcn_global_load_lds(
      (const __attribute__((address_space(1))) void*)g,
      (__attribute__((address_space(3))) void*)l, 16, 0, 0);
}

// ---- pre-pass: packed swizzled tile images [K 8KB | (V/N)^T 8KB]. ----
__global__ void build_tiles(const float* __restrict__ tk,
                            const float* __restrict__ tv,
                            ushort* __restrict__ tiles,
                            const int* __restrict__ offsets,
                            const int* __restrict__ pN) {
  const int mt = blockIdx.x, h = blockIdx.y, b = blockIdx.z;
  const int off = offsets[b];
  const int L   = offsets[b + 1] - off;
  if (mt * 64 >= L) return;
  const int tid = threadIdx.x;
  const float invN = 1.0f / (float)pN[0];

  __shared__ ushort tr[64][66];

  ushort* img = tiles + (size_t)((b * NORD + mt) * HH + h) * TILE_HW;
  const int row = tid >> 2;
  const int c0  = (tid & 3) * 16;
  const int m   = mt * 64 + row;
  const int sw  = (row & 7) << 3;

  {
    uint u[8];
    if (m < L) {
      const float* s = tk + (size_t)(off + m) * STRIDE + h * DDIM + c0;
      float4 a = *(const float4*)(s),      b4 = *(const float4*)(s + 4);
      float4 c4 = *(const float4*)(s + 8), d4 = *(const float4*)(s + 12);
      u[0] = pk2(a.x, a.y);   u[1] = pk2(a.z, a.w);
      u[2] = pk2(b4.x, b4.y); u[3] = pk2(b4.z, b4.w);
      u[4] = pk2(c4.x, c4.y); u[5] = pk2(c4.z, c4.w);
      u[6] = pk2(d4.x, d4.y); u[7] = pk2(d4.z, d4.w);
    } else {
#pragma unroll
      for (int j = 0; j < 8; ++j) u[j] = 0u;
    }
    *(uint4*)&img[row * 64 + (c0 ^ sw)]       = make_uint4(u[0], u[1], u[2], u[3]);
    *(uint4*)&img[row * 64 + ((c0 + 8) ^ sw)] = make_uint4(u[4], u[5], u[6], u[7]);
  }
  {
    uint u[8];
    if (m < L) {
      const float* s = tv + (size_t)(off + m) * STRIDE + h * DDIM + c0;
      float4 a = *(const float4*)(s),      b4 = *(const float4*)(s + 4);
      float4 c4 = *(const float4*)(s + 8), d4 = *(const float4*)(s + 12);
      u[0] = pk2(a.x * invN, a.y * invN);   u[1] = pk2(a.z * invN, a.w * invN);
      u[2] = pk2(b4.x * invN, b4.y * invN); u[3] = pk2(b4.z * invN, b4.w * invN);
      u[4] = pk2(c4.x * invN, c4.y * invN); u[5] = pk2(c4.z * invN, c4.w * invN);
      u[6] = pk2(d4.x * invN, d4.y * invN); u[7] = pk2(d4.z * invN, d4.w * invN);
    } else {
#pragma unroll
      for (int j = 0; j < 8; ++j) u[j] = 0u;
    }
#pragma unroll
    for (int j = 0; j < 8; ++j) *(uint*)&tr[row][c0 + 2 * j] = u[j];
  }
  __syncthreads();
  {
    const int dv = tid >> 2;
    const int tc = (tid & 3) * 16;
    uint u[8];
#pragma unroll
    for (int j = 0; j < 8; ++j)
      u[j] = (uint)tr[tc + 2 * j][dv] | ((uint)tr[tc + 2 * j + 1][dv] << 16);
    *(uint4*)&img[4096 + row * 64 + (tc ^ sw)]       = make_uint4(u[0], u[1], u[2], u[3]);
    *(uint4*)&img[4096 + row * 64 + ((tc + 8) ^ sw)] = make_uint4(u[4], u[5], u[6], u[7]);
  }
}

__global__ void zero_ctr(uint* ctr) { *ctr = 0u; }

// ---- main: QT=64, single-buffered KV (6 blocks/CU), self-scheduled ----
__launch_bounds__(256, 6)
__global__ void hstu_s(const float* __restrict__ tq,
                       const ushort* __restrict__ tiles,
                       const int* __restrict__ offsets,
                       const int* __restrict__ ncand,
                       const int* __restrict__ nctx,
                       float* __restrict__ out, int Tm1, int Bb) {
  __shared__ ushort KV[TILE_HW];     // single-buffered [K 8KB | V^T 8KB] 16 KB
  __shared__ ushort Ps[4 * 1024];    // per-wave P strips; head = sched scratch

  const int tid  = threadIdx.x;
  const int w    = tid >> 6;
  const int lane = tid & 63;
  const int lo   = lane & 15;
  const int hi   = lane >> 4;

  // ---- derive this block's items (R11 snake, closed form), parallel ranking.
  int* scr = (int*)Ps;
  if (tid < 16)
    scr[tid] = (tid < Bb) ? (offsets[tid + 1] - offsets[tid] + QT - 1) / QT : 0;
  if (tid >= 16 && tid < 32) scr[tid] = -1;
  __syncthreads();
  if (tid < Bb) {
    const int nqb = scr[tid];
    int r = 0;
#pragma unroll
    for (int j = 0; j < 16; ++j) {
      int v = scr[j];
      r += (j < Bb) & ((v > nqb) | ((v == nqb) & (j < tid)));
    }
    if (r < Bb / 2) scr[16 + (r & 7)] = tid;
    else            scr[24 + ((Bb - 1 - r) & 7)] = tid;
  }
  __syncthreads();
  if (tid == 0) {
    const int g = blockIdx.x & 7, lb = blockIdx.x >> 3;
    const int gb0 = scr[16 + g], gb1 = scr[24 + g];
    const int q0 = (gb0 >= 0) ? scr[gb0] : -1;
    const int q1 = (gb1 >= 0) ? scr[gb1] : -1;
    const int i0 = lb >> 3,         h0 = lb & 7;
    const int i1 = (255 - lb) >> 3, h1 = (255 - lb) & 7;
    int cnt = 0, i = 0, e0 = -1, e1 = -1;
#pragma unroll
    for (int cst = 16; cst >= 1; --cst) {
#pragma unroll
      for (int s = 0; s < 2; ++s) {
        const int bb = (s == 0) ? gb0 : gb1;
        const int q  = (s == 0) ? q0 : q1;
        if (bb < 0) continue;
#pragma unroll
        for (int which = 0; which < 2; ++which) {
          int qt = -1;
          if (which == 0 && cst == q) qt = 0;              // contextual full sweep
          if (which == 1 && cst >= 2 && cst <= q) qt = cst - 1;
          if (qt < 0) continue;
          const int enc = (bb << 7) | qt;
          if (i == i0) { e0 = enc | (h0 << 4); ++cnt; }
          if (i == i1) { e1 = enc | (h1 << 4); ++cnt; }
          ++i;
        }
      }
    }
    if (e0 < 0) { e0 = e1; e1 = -1; }
    scr[32] = e0; scr[33] = e1; scr[34] = cnt;
  }
  __syncthreads();
  const int e0  = scr[32];
  const int e1  = scr[33];
  const int cnt = scr[34];
  if (cnt == 0) return;

  ushort* Pw = &Ps[w * 1024];

  for (int it = 0; it < cnt; ++it) {
    const int e = (it == 0) ? e0 : e1;
    if (e < 0) return;
    const int b = (e >> 7) & 15, h = (e >> 4) & 7, qt = e & 15;
    const int off = offsets[b];
    const int L   = offsets[b + 1] - off;
    const int n0  = qt * QT;
    if (n0 >= L) continue;

    const int c = nctx[b];
    const int M = L - c + 1 - ncand[b];
    const int m_hi  = (n0 < c) ? L : min(n0 + QT, L);
    const int niter = (m_hi + KT - 1) / KT;

    const ushort* ibase = tiles + (size_t)(b * NORD * HH + h) * TILE_HW;

    // Q -> registers (frag: q-row = n0 + w*16 + lo, k = ks*32 + hi*8 + 0..7)
    short8 qf[2];
    {
      int qr = min(off + n0 + w * 16 + lo, Tm1);
      const float* qp = tq + (size_t)qr * STRIDE + h * DDIM + hi * 8;
      float4 qa = *(const float4*)(qp);
      float4 qb = *(const float4*)(qp + 4);
      float4 qc = *(const float4*)(qp + 32);
      float4 qd = *(const float4*)(qp + 36);
      u32x4 v0 = {pk2(qa.x, qa.y), pk2(qa.z, qa.w), pk2(qb.x, qb.y), pk2(qb.z, qb.w)};
      u32x4 v1 = {pk2(qc.x, qc.y), pk2(qc.z, qc.w), pk2(qd.x, qd.y), pk2(qd.z, qd.w)};
      qf[0] = __builtin_bit_cast(short8, v0);
      qf[1] = __builtin_bit_cast(short8, v1);
    }

    // per-lane mask scalars (q-row = n): valid = nok & ((m < thr) | (m == n))
    const int  n   = n0 + w * 16 + lo;
    const int  an  = min(max(n - c + 1, 0), M);
    const int  thr = (an > 0 ? an : M) + c - 1;
    const bool nok = n < L;

    f32x4 oacc[4];
#pragma unroll
    for (int i2 = 0; i2 < 4; ++i2) oacc[i2] = (f32x4){0.f, 0.f, 0.f, 0.f};

    for (int t = 0; t < niter; ++t) {
      __syncthreads();   // all waves done reading KV (prev iter / prev item)

      // stage tile t (single buffer); barrier below drains each wave's DMA
      {
        const ushort* src = ibase + (size_t)t * (HH * TILE_HW) + w * 2048 + lane * 8;
        ushort* dst = &KV[w * 2048];
#pragma unroll
        for (int i2 = 0; i2 < 4; ++i2) dma16(src + i2 * 512, dst + i2 * 512);
      }
      __syncthreads();   // KV[t] visible; TLP (6 blocks/CU) hides the drain

      const ushort* Kb = KV;
      const ushort* Vb = KV + 4096;
      const int m0 = t * KT;

      // wave-uniform all-valid test: every lane's rows fully below threshold
      const bool fast = __all((m0 + 63) < thr);

      // S^T = K Q^T (swapped): lane holds P[q=lo][m = m0+kc*16+4*hi+r]
#pragma unroll
      for (int kc = 0; kc < 4; ++kc) {
        const int krw = kc * 16 + lo;
        const int ksw = (krw & 7) << 3;
        short8 kf0 = *(const short8*)&Kb[krw * 64 + ((hi * 8) ^ ksw)];
        short8 kf1 = *(const short8*)&Kb[krw * 64 + ((32 + hi * 8) ^ ksw)];
        f32x4 s4 = (f32x4){0.f, 0.f, 0.f, 0.f};
        s4 = __builtin_amdgcn_mfma_f32_16x16x32_bf16(kf0, qf[0], s4, 0, 0, 0);
        s4 = __builtin_amdgcn_mfma_f32_16x16x32_bf16(kf1, qf[1], s4, 0, 0, 0);
        float pp[4];
        if (fast) {
#pragma unroll
          for (int r = 0; r < 4; ++r) {
            float s = s4[r];
            pp[r] = s * __builtin_amdgcn_rcpf(1.f + __expf(-s));
          }
        } else {
          const int mb = m0 + kc * 16 + 4 * hi;
#pragma unroll
          for (int r = 0; r < 4; ++r) {
            const int mm = mb + r;
            const bool valid = nok & ((mm < thr) | (mm == n));
            float s = valid ? s4[r] : 0.f;   // silu(0)=0; no NaN path
            pp[r] = s * __builtin_amdgcn_rcpf(1.f + __expf(-s));
          }
        }
        const int col = kc * 16 + 4 * hi;    // 4-aligned -> 8B packed write
        *(uint2*)&Pw[lo * 64 + (col ^ ((lo & 7) << 3))] =
            make_uint2(pk2(pp[0], pp[1]), pk2(pp[2], pp[3]));
      }

      // O += P V (wave-private P round-trip, no barrier)
#pragma unroll
      for (int mc = 0; mc < 2; ++mc) {
        short8 pf = *(const short8*)&Pw[lo * 64 + ((mc * 32 + hi * 8) ^ ((lo & 7) << 3))];
#pragma unroll
        for (int dvc = 0; dvc < 4; ++dvc) {
          const int vrow = dvc * 16 + lo;
          short8 vf = *(const short8*)&Vb[vrow * 64 + ((mc * 32 + hi * 8) ^ ((vrow & 7) << 3))];
          oacc[dvc] = __builtin_amdgcn_mfma_f32_16x16x32_bf16(pf, vf, oacc[dvc], 0, 0, 0);
        }
      }
    }

    // write out (fp32), C-frag layout: row q = 4*hi+r, col dv = dvc*16+lo
#pragma unroll
    for (int dvc = 0; dvc < 4; ++dvc) {
#pragma unroll
      for (int r = 0; r < 4; ++r) {
        int nn = n0 + w * 16 + hi * 4 + r;
        if (nn < L)
          out[(size_t)(off + nn) * STRIDE + h * DDIM + dvc * 16 + lo] = oacc[dvc][r];
      }
    }
  }
}

// ---- fallback (ws too small / B>16): reg-staged fp32 queue path ----
__launch_bounds__(256)
__global__ void hstu_fb(const float* __restrict__ tq,
                        const float* __restrict__ tk,
                        const float* __restrict__ tv,
                        const int* __restrict__ offsets,
                        const int* __restrict__ pN,
                        const int* __restrict__ ncand,
                        const int* __restrict__ nctx,
                        float* __restrict__ out,
                        uint* __restrict__ ctr,
                        int Tm1, int Bb) {
  const int bhc    = Bb * HH;
  const int nitems = NORD * bhc;

  __shared__ ushort Ks[KT * DDIM];
  __shared__ ushort Vt[DDIM * KT];
  __shared__ ushort Ps[4 * 1024];
  __shared__ int s_item;

  const int tid  = threadIdx.x;
  const int w    = tid >> 6;
  const int lane = tid & 63;
  const int lo   = lane & 15;
  const int hi   = lane >> 4;
  const float invN = 1.0f / (float)pN[0];
  ushort* Pw = &Ps[w * 1024];

  for (;;) {
    __syncthreads();
    if (tid == 0) s_item = (int)atomicAdd(ctr, 1u);
    __syncthreads();
    const int item = s_item;
    if (item >= nitems) return;
    const int ord = item / bhc;
    const int rem = item - ord * bhc;
    const int b = rem / HH, h = rem - b * HH;
    const int qt = (ord == 0) ? 0 : (NORD - ord);
    const int off = offsets[b];
    const int L   = offsets[b + 1] - off;
    const int n0  = qt * QT;
    if (n0 >= L) continue;

    const int c = nctx[b];
    const int M = L - c + 1 - ncand[b];
    const int m_hi  = (n0 < c) ? L : min(n0 + QT, L);
    const int niter = (m_hi + KT - 1) / KT;

    short8 qf[2];
    {
      int qr = min(off + n0 + w * 16 + lo, Tm1);
      const float* qp = tq + (size_t)qr * STRIDE + h * DDIM + hi * 8;
      float4 qa = *(const float4*)(qp);
      float4 qb = *(const float4*)(qp + 4);
      float4 qc = *(const float4*)(qp + 32);
      float4 qd = *(const float4*)(qp + 36);
      u32x4 v0 = {pk2(qa.x, qa.y), pk2(qa.z, qa.w), pk2(qb.x, qb.y), pk2(qb.z, qb.w)};
      u32x4 v1 = {pk2(qc.x, qc.y), pk2(qc.z, qc.w), pk2(qd.x, qd.y), pk2(qd.z, qd.w)};
      qf[0] = __builtin_bit_cast(short8, v0);
      qf[1] = __builtin_bit_cast(short8, v1);
    }

    const int  n   = n0 + w * 16 + lo;
    const int  an  = min(max(n - c + 1, 0), M);
    const int  thr = (an > 0 ? an : M) + c - 1;
    const bool nok = n < L;

    f32x4 oacc[4];
#pragma unroll
    for (int i = 0; i < 4; ++i) oacc[i] = (f32x4){0.f, 0.f, 0.f, 0.f};

    for (int t = 0; t < niter; ++t) {
      const int m0 = t * KT;
      __syncthreads();
#pragma unroll
      for (int jj = 0; jj < 4; ++jj) {
        int row = (tid >> 4) + jj * 16;
        int r2  = min(off + m0 + row, Tm1);
        float4 kv = *(const float4*)(tk + (size_t)r2 * STRIDE + h * DDIM + (tid & 15) * 4);
        uint2 pk;
        pk.x = pk2(kv.x, kv.y);
        pk.y = pk2(kv.z, kv.w);
        *(uint2*)&Ks[row * 64 + (((tid & 15) * 4) ^ ((row & 7) << 3))] = pk;
      }
      {
        uint bb[8];
#pragma unroll
        for (int j = 0; j < 8; ++j) {
          int ra = min(off + m0 + w * 16 + 2 * j,     Tm1);
          int rb = min(off + m0 + w * 16 + 2 * j + 1, Tm1);
          float va = tv[(size_t)ra * STRIDE + h * DDIM + lane];
          float vb = tv[(size_t)rb * STRIDE + h * DDIM + lane];
          bb[j] = pk2(va, vb);
        }
        int s = (lane & 7) << 3;
        *(uint4*)&Vt[lane * 64 + ((w * 16)     ^ s)] = make_uint4(bb[0], bb[1], bb[2], bb[3]);
        *(uint4*)&Vt[lane * 64 + ((w * 16 + 8) ^ s)] = make_uint4(bb[4], bb[5], bb[6], bb[7]);
      }
      __syncthreads();

#pragma unroll
      for (int kc = 0; kc < 4; ++kc) {
        const int krw = kc * 16 + lo;
        const int ksw = (krw & 7) << 3;
        short8 kf0 = *(const short8*)&Ks[krw * 64 + ((hi * 8) ^ ksw)];
        short8 kf1 = *(const short8*)&Ks[krw * 64 + ((32 + hi * 8) ^ ksw)];
        f32x4 s4 = (f32x4){0.f, 0.f, 0.f, 0.f};
        s4 = __builtin_amdgcn_mfma_f32_16x16x32_bf16(kf0, qf[0], s4, 0, 0, 0);
        s4 = __builtin_amdgcn_mfma_f32_16x16x32_bf16(kf1, qf[1], s4, 0, 0, 0);
        const int mb = m0 + kc * 16 + 4 * hi;
        float pp[4];
#pragma unroll
        for (int r = 0; r < 4; ++r) {
          const int mm = mb + r;
          const bool valid = nok & ((mm < thr) | (mm == n));
          float s = valid ? s4[r] : 0.f;
          pp[r] = s * invN * __builtin_amdgcn_rcpf(1.f + __expf(-s));
        }
        const int col = kc * 16 + 4 * hi;
        *(uint2*)&Pw[lo * 64 + (col ^ ((lo & 7) << 3))] =
            make_uint2(pk2(pp[0], pp[1]), pk2(pp[2], pp[3]));
      }

#pragma unroll
      for (int mc = 0; mc < 2; ++mc) {
        short8 pf = *(const short8*)&Pw[lo * 64 + ((mc * 32 + hi * 8) ^ ((lo & 7) << 3))];
#pragma unroll
        for (int dvc = 0; dvc < 4; ++dvc) {
          const int vrow = dvc * 16 + lo;
          short8 vf = *(const short8*)&Vt[vrow * 64 + ((mc * 32 + hi * 8) ^ ((vrow & 7) << 3))];
          oacc[dvc] = __builtin_amdgcn_mfma_f32_16x16x32_bf16(pf, vf, oacc[dvc], 0, 0, 0);
        }
      }
    }

#pragma unroll
    for (int dvc = 0; dvc < 4; ++dvc) {
#pragma unroll
      for (int r = 0; r < 4; ++r) {
        int nn = n0 + w * 16 + hi * 4 + r;
        if (nn < L)
          out[(size_t)(off + nn) * STRIDE + h * DDIM + dvc * 16 + lo] = oacc[dvc][r];
      }
    }
  }
}

extern "C" void kernel_launch(void* const* d_in, const int* in_sizes, int n_in,
                              void* d_out, int out_size, void* d_ws, size_t ws_size,
                              hipStream_t stream) {
  const float* tq      = (const float*)d_in[0];
  const float* tk      = (const float*)d_in[1];
  const float* tv      = (const float*)d_in[2];
  const int*   offsets = (const int*)d_in[3];
  const int*   pN      = (const int*)d_in[4];
  const int*   ncand   = (const int*)d_in[5];
  const int*   nctx    = (const int*)d_in[6];
  float*       out     = (float*)d_out;

  const int B = in_sizes[3] - 1;
  const int T = in_sizes[0] / STRIDE;

  uint*   ctr   = (uint*)d_ws;
  ushort* tiles = (ushort*)((char*)d_ws + 256);
  const size_t need = 256 + (size_t)B * NORD * HH * TILE_HW * sizeof(ushort);

  dim3 block(256);

  if (ws_size >= need && B <= 16) {
    dim3 tgrid(NORD, HH, B);
    build_tiles<<<tgrid, block, 0, stream>>>(tk, tv, tiles, offsets, pN);
    hstu_s<<<NBLK, block, 0, stream>>>(tq, tiles, offsets, ncand, nctx, out,
                                       T - 1, B);
  } else {
    zero_ctr<<<1, 1, 0, stream>>>(ctr);
    hstu_fb<<<NBLK, block, 0, stream>>>(tq, tk, tv, offsets, pN, ncand,
                                        nctx, out, ctr, T - 1, B);
  }
}

// Round 20
// 53.058 us; speedup vs baseline: 1.4545x; 1.0945x over previous
//
#include <hip/hip_runtime.h>
#include <math.h>

// HSTU jagged attention, MFMA bf16, DMA-staged tile images, self-scheduled.
// out = (silu(Q K^T) / N * mask) V, no softmax. H=8, D=DV=64, N=1024.
// Mask (exact collapse): valid(n,m) = (m < thr(n)) | (m == n),
//   thr(n) = (an>0 ? an : M) + c - 1, an = clamp(n-c+1,0,M), M = L-c+1-ncand.
// R20: exact R17 structure (dbuf KV, (256,4) - the only spill-free allocator
// point; R13/R19 showed any higher occupancy target spills) + wave-uniform
// all-valid fast path (skip mask on interior tiles, ~75-80% of iterations).

#define HH      8
#define DDIM    64
#define QT      64
#define KT      64
#define STRIDE  512
#define NMAX    1024
#define NORD    16
#define TILE_HW 8192          // ushorts per tile image (16 KB)
#define NBLK    1024

typedef __attribute__((ext_vector_type(8))) short short8;
typedef __attribute__((ext_vector_type(4))) float f32x4;
typedef __attribute__((ext_vector_type(4))) uint  u32x4;

static __device__ __forceinline__ uint pk2(float a, float b) {
  uint r;
  asm("v_cvt_pk_bf16_f32 %0, %1, %2" : "=v"(r) : "v"(a), "v"(b));
  return r;
}

static __device__ __forceinline__ void dma16(const ushort* g, ushort* l) {
  __builtin_amdgcn_global_load_lds(
      (const __attribute__((address_space(1))) void*)g,
      (__attribute__((address_space(3))) void*)l, 16, 0, 0);
}

// ---- pre-pass: packed swizzled tile images [K 8KB | (V/N)^T 8KB]. ----
__global__ void build_tiles(const float* __restrict__ tk,
                            const float* __restrict__ tv,
                            ushort* __restrict__ tiles,
                            const int* __restrict__ offsets,
                            const int* __restrict__ pN) {
  const int mt = blockIdx.x, h = blockIdx.y, b = blockIdx.z;
  const int off = offsets[b];
  const int L   = offsets[b + 1] - off;
  if (mt * 64 >= L) return;
  const int tid = threadIdx.x;
  const float invN = 1.0f / (float)pN[0];

  __shared__ ushort tr[64][66];

  ushort* img = tiles + (size_t)((b * NORD + mt) * HH + h) * TILE_HW;
  const int row = tid >> 2;
  const int c0  = (tid & 3) * 16;
  const int m   = mt * 64 + row;
  const int sw  = (row & 7) << 3;

  {
    uint u[8];
    if (m < L) {
      const float* s = tk + (size_t)(off + m) * STRIDE + h * DDIM + c0;
      float4 a = *(const float4*)(s),      b4 = *(const float4*)(s + 4);
      float4 c4 = *(const float4*)(s + 8), d4 = *(const float4*)(s + 12);
      u[0] = pk2(a.x, a.y);   u[1] = pk2(a.z, a.w);
      u[2] = pk2(b4.x, b4.y); u[3] = pk2(b4.z, b4.w);
      u[4] = pk2(c4.x, c4.y); u[5] = pk2(c4.z, c4.w);
      u[6] = pk2(d4.x, d4.y); u[7] = pk2(d4.z, d4.w);
    } else {
#pragma unroll
      for (int j = 0; j < 8; ++j) u[j] = 0u;
    }
    *(uint4*)&img[row * 64 + (c0 ^ sw)]       = make_uint4(u[0], u[1], u[2], u[3]);
    *(uint4*)&img[row * 64 + ((c0 + 8) ^ sw)] = make_uint4(u[4], u[5], u[6], u[7]);
  }
  {
    uint u[8];
    if (m < L) {
      const float* s = tv + (size_t)(off + m) * STRIDE + h * DDIM + c0;
      float4 a = *(const float4*)(s),      b4 = *(const float4*)(s + 4);
      float4 c4 = *(const float4*)(s + 8), d4 = *(const float4*)(s + 12);
      u[0] = pk2(a.x * invN, a.y * invN);   u[1] = pk2(a.z * invN, a.w * invN);
      u[2] = pk2(b4.x * invN, b4.y * invN); u[3] = pk2(b4.z * invN, b4.w * invN);
      u[4] = pk2(c4.x * invN, c4.y * invN); u[5] = pk2(c4.z * invN, c4.w * invN);
      u[6] = pk2(d4.x * invN, d4.y * invN); u[7] = pk2(d4.z * invN, d4.w * invN);
    } else {
#pragma unroll
      for (int j = 0; j < 8; ++j) u[j] = 0u;
    }
#pragma unroll
    for (int j = 0; j < 8; ++j) *(uint*)&tr[row][c0 + 2 * j] = u[j];
  }
  __syncthreads();
  {
    const int dv = tid >> 2;
    const int tc = (tid & 3) * 16;
    uint u[8];
#pragma unroll
    for (int j = 0; j < 8; ++j)
      u[j] = (uint)tr[tc + 2 * j][dv] | ((uint)tr[tc + 2 * j + 1][dv] << 16);
    *(uint4*)&img[4096 + row * 64 + (tc ^ sw)]       = make_uint4(u[0], u[1], u[2], u[3]);
    *(uint4*)&img[4096 + row * 64 + ((tc + 8) ^ sw)] = make_uint4(u[4], u[5], u[6], u[7]);
  }
}

__global__ void zero_ctr(uint* ctr) { *ctr = 0u; }

// ---- main: DMA-staged tile images, self-scheduled (parallel derivation) ----
__launch_bounds__(256, 4)
__global__ void hstu_s(const float* __restrict__ tq,
                       const ushort* __restrict__ tiles,
                       const int* __restrict__ offsets,
                       const int* __restrict__ ncand,
                       const int* __restrict__ nctx,
                       float* __restrict__ out, int Tm1, int Bb) {
  __shared__ ushort KV[2][TILE_HW];  // double-buffered [K 8KB | V^T 8KB]  32 KB
  __shared__ ushort Ps[4 * 1024];    // per-wave P strips; head = sched scratch

  const int tid  = threadIdx.x;
  const int w    = tid >> 6;
  const int lane = tid & 63;
  const int lo   = lane & 15;
  const int hi   = lane >> 4;

  // ---- derive this block's items (R11 snake, closed form), PARALLEL ranking.
  int* scr = (int*)Ps;
  if (tid < 16)
    scr[tid] = (tid < Bb) ? (offsets[tid + 1] - offsets[tid] + QT - 1) / QT : 0;
  if (tid >= 16 && tid < 32) scr[tid] = -1;
  __syncthreads();
  if (tid < Bb) {
    const int nqb = scr[tid];
    int r = 0;
#pragma unroll
    for (int j = 0; j < 16; ++j) {
      int v = scr[j];
      r += (j < Bb) & ((v > nqb) | ((v == nqb) & (j < tid)));
    }
    if (r < Bb / 2) scr[16 + (r & 7)] = tid;
    else            scr[24 + ((Bb - 1 - r) & 7)] = tid;
  }
  __syncthreads();
  if (tid == 0) {
    const int g = blockIdx.x & 7, lb = blockIdx.x >> 3;
    const int gb0 = scr[16 + g], gb1 = scr[24 + g];
    const int q0 = (gb0 >= 0) ? scr[gb0] : -1;
    const int q1 = (gb1 >= 0) ? scr[gb1] : -1;
    const int i0 = lb >> 3,         h0 = lb & 7;
    const int i1 = (255 - lb) >> 3, h1 = (255 - lb) & 7;
    int cnt = 0, i = 0, e0 = -1, e1 = -1;
#pragma unroll
    for (int cst = 16; cst >= 1; --cst) {
#pragma unroll
      for (int s = 0; s < 2; ++s) {
        const int bb = (s == 0) ? gb0 : gb1;
        const int q  = (s == 0) ? q0 : q1;
        if (bb < 0) continue;
#pragma unroll
        for (int which = 0; which < 2; ++which) {
          int qt = -1;
          if (which == 0 && cst == q) qt = 0;              // contextual full sweep
          if (which == 1 && cst >= 2 && cst <= q) qt = cst - 1;
          if (qt < 0) continue;
          const int enc = (bb << 7) | qt;
          if (i == i0) { e0 = enc | (h0 << 4); ++cnt; }
          if (i == i1) { e1 = enc | (h1 << 4); ++cnt; }
          ++i;
        }
      }
    }
    if (e0 < 0) { e0 = e1; e1 = -1; }
    scr[32] = e0; scr[33] = e1; scr[34] = cnt;
  }
  __syncthreads();
  const int e0  = scr[32];
  const int e1  = scr[33];
  const int cnt = scr[34];
  if (cnt == 0) return;

  ushort* Pw = &Ps[w * 1024];

  for (int it = 0; it < cnt; ++it) {
    const int e = (it == 0) ? e0 : e1;
    if (e < 0) return;
    const int b = (e >> 7) & 15, h = (e >> 4) & 7, qt = e & 15;
    const int off = offsets[b];
    const int L   = offsets[b + 1] - off;
    const int n0  = qt * QT;
    if (n0 >= L) continue;

    const int c = nctx[b];
    const int M = L - c + 1 - ncand[b];
    const int m_hi  = (n0 < c) ? L : min(n0 + QT, L);
    const int niter = (m_hi + KT - 1) / KT;

    const ushort* ibase = tiles + (size_t)(b * NORD * HH + h) * TILE_HW;

    __syncthreads();                         // prev item's LDS fully consumed

    // prologue: DMA tile 0 into KV[0]
    {
      const ushort* src = ibase + w * 2048 + lane * 8;
      ushort* dst = &KV[0][w * 2048];
#pragma unroll
      for (int i2 = 0; i2 < 4; ++i2) dma16(src + i2 * 512, dst + i2 * 512);
    }

    // Q -> registers (frag: q-row = n0 + w*16 + lo, k = ks*32 + hi*8 + 0..7)
    short8 qf[2];
    {
      int qr = min(off + n0 + w * 16 + lo, Tm1);
      const float* qp = tq + (size_t)qr * STRIDE + h * DDIM + hi * 8;
      float4 qa = *(const float4*)(qp);
      float4 qb = *(const float4*)(qp + 4);
      float4 qc = *(const float4*)(qp + 32);
      float4 qd = *(const float4*)(qp + 36);
      u32x4 v0 = {pk2(qa.x, qa.y), pk2(qa.z, qa.w), pk2(qb.x, qb.y), pk2(qb.z, qb.w)};
      u32x4 v1 = {pk2(qc.x, qc.y), pk2(qc.z, qc.w), pk2(qd.x, qd.y), pk2(qd.z, qd.w)};
      qf[0] = __builtin_bit_cast(short8, v0);
      qf[1] = __builtin_bit_cast(short8, v1);
    }

    // per-lane mask scalars (q-row = n): valid = nok & ((m < thr) | (m == n))
    const int  n   = n0 + w * 16 + lo;
    const int  an  = min(max(n - c + 1, 0), M);
    const int  thr = (an > 0 ? an : M) + c - 1;
    const bool nok = n < L;

    f32x4 oacc[4];
#pragma unroll
    for (int i2 = 0; i2 < 4; ++i2) oacc[i2] = (f32x4){0.f, 0.f, 0.f, 0.f};

    for (int t = 0; t < niter; ++t) {
      __syncthreads();   // drains tile-t DMA; gates buf (t+1)&1 reuse

      if (t + 1 < niter) {
        const ushort* src = ibase + (size_t)(t + 1) * (HH * TILE_HW)
                            + w * 2048 + lane * 8;
        ushort* dst = &KV[(t + 1) & 1][w * 2048];
#pragma unroll
        for (int i2 = 0; i2 < 4; ++i2) dma16(src + i2 * 512, dst + i2 * 512);
      }

      const ushort* Kb = KV[t & 1];
      const ushort* Vb = Kb + 4096;
      const int m0 = t * KT;

      // wave-uniform all-valid test: entire K-tile below every lane's threshold
      const bool fast = __all((m0 + 63) < thr);

      // S^T = K Q^T (swapped): lane holds P[q=lo][m = m0+kc*16+4*hi+r]
#pragma unroll
      for (int kc = 0; kc < 4; ++kc) {
        const int krw = kc * 16 + lo;
        const int ksw = (krw & 7) << 3;
        short8 kf0 = *(const short8*)&Kb[krw * 64 + ((hi * 8) ^ ksw)];
        short8 kf1 = *(const short8*)&Kb[krw * 64 + ((32 + hi * 8) ^ ksw)];
        f32x4 s4 = (f32x4){0.f, 0.f, 0.f, 0.f};
        s4 = __builtin_amdgcn_mfma_f32_16x16x32_bf16(kf0, qf[0], s4, 0, 0, 0);
        s4 = __builtin_amdgcn_mfma_f32_16x16x32_bf16(kf1, qf[1], s4, 0, 0, 0);
        float pp[4];
        if (fast) {
          // all (q,m) valid; zero-padded K rows give s=0 -> silu(0)=0 exactly
#pragma unroll
          for (int r = 0; r < 4; ++r) {
            float s = s4[r];
            pp[r] = s * __builtin_amdgcn_rcpf(1.f + __expf(-s));
          }
        } else {
          const int mb = m0 + kc * 16 + 4 * hi;
#pragma unroll
          for (int r = 0; r < 4; ++r) {
            const int mm = mb + r;
            const bool valid = nok & ((mm < thr) | (mm == n));
            float s = valid ? s4[r] : 0.f;   // silu(0)=0; no NaN path
            pp[r] = s * __builtin_amdgcn_rcpf(1.f + __expf(-s));
          }
        }
        const int col = kc * 16 + 4 * hi;    // 4-aligned -> 8B packed write
        *(uint2*)&Pw[lo * 64 + (col ^ ((lo & 7) << 3))] =
            make_uint2(pk2(pp[0], pp[1]), pk2(pp[2], pp[3]));
      }

      // O += P V (wave-private P round-trip, no barrier)
#pragma unroll
      for (int mc = 0; mc < 2; ++mc) {
        short8 pf = *(const short8*)&Pw[lo * 64 + ((mc * 32 + hi * 8) ^ ((lo & 7) << 3))];
#pragma unroll
        for (int dvc = 0; dvc < 4; ++dvc) {
          const int vrow = dvc * 16 + lo;
          short8 vf = *(const short8*)&Vb[vrow * 64 + ((mc * 32 + hi * 8) ^ ((vrow & 7) << 3))];
          oacc[dvc] = __builtin_amdgcn_mfma_f32_16x16x32_bf16(pf, vf, oacc[dvc], 0, 0, 0);
        }
      }
    }

    // write out (fp32), C-frag layout: row q = 4*hi+r, col dv = dvc*16+lo
#pragma unroll
    for (int dvc = 0; dvc < 4; ++dvc) {
#pragma unroll
      for (int r = 0; r < 4; ++r) {
        int nn = n0 + w * 16 + hi * 4 + r;
        if (nn < L)
          out[(size_t)(off + nn) * STRIDE + h * DDIM + dvc * 16 + lo] = oacc[dvc][r];
      }
    }
  }
}

// ---- fallback (ws too small / B>16): reg-staged fp32 queue path ----
__launch_bounds__(256)
__global__ void hstu_fb(const float* __restrict__ tq,
                        const float* __restrict__ tk,
                        const float* __restrict__ tv,
                        const int* __restrict__ offsets,
                        const int* __restrict__ pN,
                        const int* __restrict__ ncand,
                        const int* __restrict__ nctx,
                        float* __restrict__ out,
                        uint* __restrict__ ctr,
                        int Tm1, int Bb) {
  const int bhc    = Bb * HH;
  const int nitems = NORD * bhc;

  __shared__ ushort Ks[KT * DDIM];
  __shared__ ushort Vt[DDIM * KT];
  __shared__ ushort Ps[4 * 1024];
  __shared__ int s_item;

  const int tid  = threadIdx.x;
  const int w    = tid >> 6;
  const int lane = tid & 63;
  const int lo   = lane & 15;
  const int hi   = lane >> 4;
  const float invN = 1.0f / (float)pN[0];
  ushort* Pw = &Ps[w * 1024];

  for (;;) {
    __syncthreads();
    if (tid == 0) s_item = (int)atomicAdd(ctr, 1u);
    __syncthreads();
    const int item = s_item;
    if (item >= nitems) return;
    const int ord = item / bhc;
    const int rem = item - ord * bhc;
    const int b = rem / HH, h = rem - b * HH;
    const int qt = (ord == 0) ? 0 : (NORD - ord);
    const int off = offsets[b];
    const int L   = offsets[b + 1] - off;
    const int n0  = qt * QT;
    if (n0 >= L) continue;

    const int c = nctx[b];
    const int M = L - c + 1 - ncand[b];
    const int m_hi  = (n0 < c) ? L : min(n0 + QT, L);
    const int niter = (m_hi + KT - 1) / KT;

    short8 qf[2];
    {
      int qr = min(off + n0 + w * 16 + lo, Tm1);
      const float* qp = tq + (size_t)qr * STRIDE + h * DDIM + hi * 8;
      float4 qa = *(const float4*)(qp);
      float4 qb = *(const float4*)(qp + 4);
      float4 qc = *(const float4*)(qp + 32);
      float4 qd = *(const float4*)(qp + 36);
      u32x4 v0 = {pk2(qa.x, qa.y), pk2(qa.z, qa.w), pk2(qb.x, qb.y), pk2(qb.z, qb.w)};
      u32x4 v1 = {pk2(qc.x, qc.y), pk2(qc.z, qc.w), pk2(qd.x, qd.y), pk2(qd.z, qd.w)};
      qf[0] = __builtin_bit_cast(short8, v0);
      qf[1] = __builtin_bit_cast(short8, v1);
    }

    const int  n   = n0 + w * 16 + lo;
    const int  an  = min(max(n - c + 1, 0), M);
    const int  thr = (an > 0 ? an : M) + c - 1;
    const bool nok = n < L;

    f32x4 oacc[4];
#pragma unroll
    for (int i = 0; i < 4; ++i) oacc[i] = (f32x4){0.f, 0.f, 0.f, 0.f};

    for (int t = 0; t < niter; ++t) {
      const int m0 = t * KT;
      __syncthreads();
#pragma unroll
      for (int jj = 0; jj < 4; ++jj) {
        int row = (tid >> 4) + jj * 16;
        int r2  = min(off + m0 + row, Tm1);
        float4 kv = *(const float4*)(tk + (size_t)r2 * STRIDE + h * DDIM + (tid & 15) * 4);
        uint2 pk;
        pk.x = pk2(kv.x, kv.y);
        pk.y = pk2(kv.z, kv.w);
        *(uint2*)&Ks[row * 64 + (((tid & 15) * 4) ^ ((row & 7) << 3))] = pk;
      }
      {
        uint bb[8];
#pragma unroll
        for (int j = 0; j < 8; ++j) {
          int ra = min(off + m0 + w * 16 + 2 * j,     Tm1);
          int rb = min(off + m0 + w * 16 + 2 * j + 1, Tm1);
          float va = tv[(size_t)ra * STRIDE + h * DDIM + lane];
          float vb = tv[(size_t)rb * STRIDE + h * DDIM + lane];
          bb[j] = pk2(va, vb);
        }
        int s = (lane & 7) << 3;
        *(uint4*)&Vt[lane * 64 + ((w * 16)     ^ s)] = make_uint4(bb[0], bb[1], bb[2], bb[3]);
        *(uint4*)&Vt[lane * 64 + ((w * 16 + 8) ^ s)] = make_uint4(bb[4], bb[5], bb[6], bb[7]);
      }
      __syncthreads();

#pragma unroll
      for (int kc = 0; kc < 4; ++kc) {
        const int krw = kc * 16 + lo;
        const int ksw = (krw & 7) << 3;
        short8 kf0 = *(const short8*)&Ks[krw * 64 + ((hi * 8) ^ ksw)];
        short8 kf1 = *(const short8*)&Ks[krw * 64 + ((32 + hi * 8) ^ ksw)];
        f32x4 s4 = (f32x4){0.f, 0.f, 0.f, 0.f};
        s4 = __builtin_amdgcn_mfma_f32_16x16x32_bf16(kf0, qf[0], s4, 0, 0, 0);
        s4 = __builtin_amdgcn_mfma_f32_16x16x32_bf16(kf1, qf[1], s4, 0, 0, 0);
        const int mb = m0 + kc * 16 + 4 * hi;
        float pp[4];
#pragma unroll
        for (int r = 0; r < 4; ++r) {
          const int mm = mb + r;
          const bool valid = nok & ((mm < thr) | (mm == n));
          float s = valid ? s4[r] : 0.f;
          pp[r] = s * invN * __builtin_amdgcn_rcpf(1.f + __expf(-s));
        }
        const int col = kc * 16 + 4 * hi;
        *(uint2*)&Pw[lo * 64 + (col ^ ((lo & 7) << 3))] =
            make_uint2(pk2(pp[0], pp[1]), pk2(pp[2], pp[3]));
      }

#pragma unroll
      for (int mc = 0; mc < 2; ++mc) {
        short8 pf = *(const short8*)&Pw[lo * 64 + ((mc * 32 + hi * 8) ^ ((lo & 7) << 3))];
#pragma unroll
        for (int dvc = 0; dvc < 4; ++dvc) {
          const int vrow = dvc * 16 + lo;
          short8 vf = *(const short8*)&Vt[vrow * 64 + ((mc * 32 + hi * 8) ^ ((vrow & 7) << 3))];
          oacc[dvc] = __builtin_amdgcn_mfma_f32_16x16x32_bf16(pf, vf, oacc[dvc], 0, 0, 0);
        }
      }
    }

#pragma unroll
    for (int dvc = 0; dvc < 4; ++dvc) {
#pragma unroll
      for (int r = 0; r < 4; ++r) {
        int nn = n0 + w * 16 + hi * 4 + r;
        if (nn < L)
          out[(size_t)(off + nn) * STRIDE + h * DDIM + dvc * 16 + lo] = oacc[dvc][r];
      }
    }
  }
}

extern "C" void kernel_launch(void* const* d_in, const int* in_sizes, int n_in,
                              void* d_out, int out_size, void* d_ws, size_t ws_size,
                              hipStream_t stream) {
  const float* tq      = (const float*)d_in[0];
  const float* tk      = (const float*)d_in[1];
  const float* tv      = (const float*)d_in[2];
  const int*   offsets = (const int*)d_in[3];
  const int*   pN      = (const int*)d_in[4];
  const int*   ncand   = (const int*)d_in[5];
  const int*   nctx    = (const int*)d_in[6];
  float*       out     = (float*)d_out;

  const int B = in_sizes[3] - 1;
  const int T = in_sizes[0] / STRIDE;

  uint*   ctr   = (uint*)d_ws;
  ushort* tiles = (ushort*)((char*)d_ws + 256);
  const size_t need = 256 + (size_t)B * NORD * HH * TILE_HW * sizeof(ushort);

  dim3 block(256);

  if (ws_size >= need && B <= 16) {
    dim3 tgrid(NORD, HH, B);
    build_tiles<<<tgrid, block, 0, stream>>>(tk, tv, tiles, offsets, pN);
    hstu_s<<<NBLK, block, 0, stream>>>(tq, tiles, offsets, ncand, nctx, out,
                                       T - 1, B);
  } else {
    zero_ctr<<<1, 1, 0, stream>>>(ctr);
    hstu_fb<<<NBLK, block, 0, stream>>>(tq, tk, tv, offsets, pN, ncand,
                                        nctx, out, ctr, T - 1, B);
  }
}

// Round 22
// 52.169 us; speedup vs baseline: 1.4793x; 1.0170x over previous
//
#include <hip/hip_runtime.h>
#include <math.h>

// HSTU jagged attention, MFMA bf16, DMA-staged tile images, self-scheduled.
// out = (silu(Q K^T) / N * mask) V, no softmax. H=8, D=DV=64, N=1024.
// Mask (exact collapse): valid(n,m) = (m < thr(n)) | (m == n),
//   thr(n) = (an>0 ? an : M) + c - 1, an = clamp(n-c+1,0,M), M = L-c+1-ncand.
// R22: R20 restored (R21's in-register-bpermute P transport produced NaN;
// reverted) + s_setprio(1) around the compute region (T5; zero-risk hint).

#define HH      8
#define DDIM    64
#define QT      64
#define KT      64
#define STRIDE  512
#define NMAX    1024
#define NORD    16
#define TILE_HW 8192          // ushorts per tile image (16 KB)
#define NBLK    1024

typedef __attribute__((ext_vector_type(8))) short short8;
typedef __attribute__((ext_vector_type(4))) float f32x4;
typedef __attribute__((ext_vector_type(4))) uint  u32x4;

static __device__ __forceinline__ uint pk2(float a, float b) {
  uint r;
  asm("v_cvt_pk_bf16_f32 %0, %1, %2" : "=v"(r) : "v"(a), "v"(b));
  return r;
}

static __device__ __forceinline__ void dma16(const ushort* g, ushort* l) {
  __builtin_amdgcn_global_load_lds(
      (const __attribute__((address_space(1))) void*)g,
      (__attribute__((address_space(3))) void*)l, 16, 0, 0);
}

// ---- pre-pass: packed swizzled tile images [K 8KB | (V/N)^T 8KB]. ----
__global__ void build_tiles(const float* __restrict__ tk,
                            const float* __restrict__ tv,
                            ushort* __restrict__ tiles,
                            const int* __restrict__ offsets,
                            const int* __restrict__ pN) {
  const int mt = blockIdx.x, h = blockIdx.y, b = blockIdx.z;
  const int off = offsets[b];
  const int L   = offsets[b + 1] - off;
  if (mt * 64 >= L) return;
  const int tid = threadIdx.x;
  const float invN = 1.0f / (float)pN[0];

  __shared__ ushort tr[64][66];

  ushort* img = tiles + (size_t)((b * NORD + mt) * HH + h) * TILE_HW;
  const int row = tid >> 2;
  const int c0  = (tid & 3) * 16;
  const int m   = mt * 64 + row;
  const int sw  = (row & 7) << 3;

  {
    uint u[8];
    if (m < L) {
      const float* s = tk + (size_t)(off + m) * STRIDE + h * DDIM + c0;
      float4 a = *(const float4*)(s),      b4 = *(const float4*)(s + 4);
      float4 c4 = *(const float4*)(s + 8), d4 = *(const float4*)(s + 12);
      u[0] = pk2(a.x, a.y);   u[1] = pk2(a.z, a.w);
      u[2] = pk2(b4.x, b4.y); u[3] = pk2(b4.z, b4.w);
      u[4] = pk2(c4.x, c4.y); u[5] = pk2(c4.z, c4.w);
      u[6] = pk2(d4.x, d4.y); u[7] = pk2(d4.z, d4.w);
    } else {
#pragma unroll
      for (int j = 0; j < 8; ++j) u[j] = 0u;
    }
    *(uint4*)&img[row * 64 + (c0 ^ sw)]       = make_uint4(u[0], u[1], u[2], u[3]);
    *(uint4*)&img[row * 64 + ((c0 + 8) ^ sw)] = make_uint4(u[4], u[5], u[6], u[7]);
  }
  {
    uint u[8];
    if (m < L) {
      const float* s = tv + (size_t)(off + m) * STRIDE + h * DDIM + c0;
      float4 a = *(const float4*)(s),      b4 = *(const float4*)(s + 4);
      float4 c4 = *(const float4*)(s + 8), d4 = *(const float4*)(s + 12);
      u[0] = pk2(a.x * invN, a.y * invN);   u[1] = pk2(a.z * invN, a.w * invN);
      u[2] = pk2(b4.x * invN, b4.y * invN); u[3] = pk2(b4.z * invN, b4.w * invN);
      u[4] = pk2(c4.x * invN, c4.y * invN); u[5] = pk2(c4.z * invN, c4.w * invN);
      u[6] = pk2(d4.x * invN, d4.y * invN); u[7] = pk2(d4.z * invN, d4.w * invN);
    } else {
#pragma unroll
      for (int j = 0; j < 8; ++j) u[j] = 0u;
    }
#pragma unroll
    for (int j = 0; j < 8; ++j) *(uint*)&tr[row][c0 + 2 * j] = u[j];
  }
  __syncthreads();
  {
    const int dv = tid >> 2;
    const int tc = (tid & 3) * 16;
    uint u[8];
#pragma unroll
    for (int j = 0; j < 8; ++j)
      u[j] = (uint)tr[tc + 2 * j][dv] | ((uint)tr[tc + 2 * j + 1][dv] << 16);
    *(uint4*)&img[4096 + row * 64 + (tc ^ sw)]       = make_uint4(u[0], u[1], u[2], u[3]);
    *(uint4*)&img[4096 + row * 64 + ((tc + 8) ^ sw)] = make_uint4(u[4], u[5], u[6], u[7]);
  }
}

__global__ void zero_ctr(uint* ctr) { *ctr = 0u; }

// ---- main: DMA-staged tile images, self-scheduled (parallel derivation) ----
__launch_bounds__(256, 4)
__global__ void hstu_s(const float* __restrict__ tq,
                       const ushort* __restrict__ tiles,
                       const int* __restrict__ offsets,
                       const int* __restrict__ ncand,
                       const int* __restrict__ nctx,
                       float* __restrict__ out, int Tm1, int Bb) {
  __shared__ ushort KV[2][TILE_HW];  // double-buffered [K 8KB | V^T 8KB]  32 KB
  __shared__ ushort Ps[4 * 1024];    // per-wave P strips; head = sched scratch

  const int tid  = threadIdx.x;
  const int w    = tid >> 6;
  const int lane = tid & 63;
  const int lo   = lane & 15;
  const int hi   = lane >> 4;

  // ---- derive this block's items (R11 snake, closed form), PARALLEL ranking.
  int* scr = (int*)Ps;
  if (tid < 16)
    scr[tid] = (tid < Bb) ? (offsets[tid + 1] - offsets[tid] + QT - 1) / QT : 0;
  if (tid >= 16 && tid < 32) scr[tid] = -1;
  __syncthreads();
  if (tid < Bb) {
    const int nqb = scr[tid];
    int r = 0;
#pragma unroll
    for (int j = 0; j < 16; ++j) {
      int v = scr[j];
      r += (j < Bb) & ((v > nqb) | ((v == nqb) & (j < tid)));
    }
    if (r < Bb / 2) scr[16 + (r & 7)] = tid;
    else            scr[24 + ((Bb - 1 - r) & 7)] = tid;
  }
  __syncthreads();
  if (tid == 0) {
    const int g = blockIdx.x & 7, lb = blockIdx.x >> 3;
    const int gb0 = scr[16 + g], gb1 = scr[24 + g];
    const int q0 = (gb0 >= 0) ? scr[gb0] : -1;
    const int q1 = (gb1 >= 0) ? scr[gb1] : -1;
    const int i0 = lb >> 3,         h0 = lb & 7;
    const int i1 = (255 - lb) >> 3, h1 = (255 - lb) & 7;
    int cnt = 0, i = 0, e0 = -1, e1 = -1;
#pragma unroll
    for (int cst = 16; cst >= 1; --cst) {
#pragma unroll
      for (int s = 0; s < 2; ++s) {
        const int bb = (s == 0) ? gb0 : gb1;
        const int q  = (s == 0) ? q0 : q1;
        if (bb < 0) continue;
#pragma unroll
        for (int which = 0; which < 2; ++which) {
          int qt = -1;
          if (which == 0 && cst == q) qt = 0;              // contextual full sweep
          if (which == 1 && cst >= 2 && cst <= q) qt = cst - 1;
          if (qt < 0) continue;
          const int enc = (bb << 7) | qt;
          if (i == i0) { e0 = enc | (h0 << 4); ++cnt; }
          if (i == i1) { e1 = enc | (h1 << 4); ++cnt; }
          ++i;
        }
      }
    }
    if (e0 < 0) { e0 = e1; e1 = -1; }
    scr[32] = e0; scr[33] = e1; scr[34] = cnt;
  }
  __syncthreads();
  const int e0  = scr[32];
  const int e1  = scr[33];
  const int cnt = scr[34];
  if (cnt == 0) return;

  ushort* Pw = &Ps[w * 1024];

  for (int it = 0; it < cnt; ++it) {
    const int e = (it == 0) ? e0 : e1;
    if (e < 0) return;
    const int b = (e >> 7) & 15, h = (e >> 4) & 7, qt = e & 15;
    const int off = offsets[b];
    const int L   = offsets[b + 1] - off;
    const int n0  = qt * QT;
    if (n0 >= L) continue;

    const int c = nctx[b];
    const int M = L - c + 1 - ncand[b];
    const int m_hi  = (n0 < c) ? L : min(n0 + QT, L);
    const int niter = (m_hi + KT - 1) / KT;

    const ushort* ibase = tiles + (size_t)(b * NORD * HH + h) * TILE_HW;

    __syncthreads();                         // prev item's LDS fully consumed

    // prologue: DMA tile 0 into KV[0]
    {
      const ushort* src = ibase + w * 2048 + lane * 8;
      ushort* dst = &KV[0][w * 2048];
#pragma unroll
      for (int i2 = 0; i2 < 4; ++i2) dma16(src + i2 * 512, dst + i2 * 512);
    }

    // Q -> registers (frag: q-row = n0 + w*16 + lo, k = ks*32 + hi*8 + 0..7)
    short8 qf[2];
    {
      int qr = min(off + n0 + w * 16 + lo, Tm1);
      const float* qp = tq + (size_t)qr * STRIDE + h * DDIM + hi * 8;
      float4 qa = *(const float4*)(qp);
      float4 qb = *(const float4*)(qp + 4);
      float4 qc = *(const float4*)(qp + 32);
      float4 qd = *(const float4*)(qp + 36);
      u32x4 v0 = {pk2(qa.x, qa.y), pk2(qa.z, qa.w), pk2(qb.x, qb.y), pk2(qb.z, qb.w)};
      u32x4 v1 = {pk2(qc.x, qc.y), pk2(qc.z, qc.w), pk2(qd.x, qd.y), pk2(qd.z, qd.w)};
      qf[0] = __builtin_bit_cast(short8, v0);
      qf[1] = __builtin_bit_cast(short8, v1);
    }

    // per-lane mask scalars (q-row = n): valid = nok & ((m < thr) | (m == n))
    const int  n   = n0 + w * 16 + lo;
    const int  an  = min(max(n - c + 1, 0), M);
    const int  thr = (an > 0 ? an : M) + c - 1;
    const bool nok = n < L;

    f32x4 oacc[4];
#pragma unroll
    for (int i2 = 0; i2 < 4; ++i2) oacc[i2] = (f32x4){0.f, 0.f, 0.f, 0.f};

    for (int t = 0; t < niter; ++t) {
      __syncthreads();   // drains tile-t DMA; gates buf (t+1)&1 reuse

      if (t + 1 < niter) {
        const ushort* src = ibase + (size_t)(t + 1) * (HH * TILE_HW)
                            + w * 2048 + lane * 8;
        ushort* dst = &KV[(t + 1) & 1][w * 2048];
#pragma unroll
        for (int i2 = 0; i2 < 4; ++i2) dma16(src + i2 * 512, dst + i2 * 512);
      }

      const ushort* Kb = KV[t & 1];
      const ushort* Vb = Kb + 4096;
      const int m0 = t * KT;

      // wave-uniform all-valid test: entire K-tile below every lane's threshold
      const bool fast = __all((m0 + 63) < thr);

      __builtin_amdgcn_s_setprio(1);   // favor compute waves over DMA-issuers

      // S^T = K Q^T (swapped): lane holds P[q=lo][m = m0+kc*16+4*hi+r]
#pragma unroll
      for (int kc = 0; kc < 4; ++kc) {
        const int krw = kc * 16 + lo;
        const int ksw = (krw & 7) << 3;
        short8 kf0 = *(const short8*)&Kb[krw * 64 + ((hi * 8) ^ ksw)];
        short8 kf1 = *(const short8*)&Kb[krw * 64 + ((32 + hi * 8) ^ ksw)];
        f32x4 s4 = (f32x4){0.f, 0.f, 0.f, 0.f};
        s4 = __builtin_amdgcn_mfma_f32_16x16x32_bf16(kf0, qf[0], s4, 0, 0, 0);
        s4 = __builtin_amdgcn_mfma_f32_16x16x32_bf16(kf1, qf[1], s4, 0, 0, 0);
        float pp[4];
        if (fast) {
          // all (q,m) valid; zero-padded K rows give s=0 -> silu(0)=0 exactly
#pragma unroll
          for (int r = 0; r < 4; ++r) {
            float s = s4[r];
            pp[r] = s * __builtin_amdgcn_rcpf(1.f + __expf(-s));
          }
        } else {
          const int mb = m0 + kc * 16 + 4 * hi;
#pragma unroll
          for (int r = 0; r < 4; ++r) {
            const int mm = mb + r;
            const bool valid = nok & ((mm < thr) | (mm == n));
            float s = valid ? s4[r] : 0.f;   // silu(0)=0; no NaN path
            pp[r] = s * __builtin_amdgcn_rcpf(1.f + __expf(-s));
          }
        }
        const int col = kc * 16 + 4 * hi;    // 4-aligned -> 8B packed write
        *(uint2*)&Pw[lo * 64 + (col ^ ((lo & 7) << 3))] =
            make_uint2(pk2(pp[0], pp[1]), pk2(pp[2], pp[3]));
      }

      // O += P V (wave-private P round-trip, no barrier)
#pragma unroll
      for (int mc = 0; mc < 2; ++mc) {
        short8 pf = *(const short8*)&Pw[lo * 64 + ((mc * 32 + hi * 8) ^ ((lo & 7) << 3))];
#pragma unroll
        for (int dvc = 0; dvc < 4; ++dvc) {
          const int vrow = dvc * 16 + lo;
          short8 vf = *(const short8*)&Vb[vrow * 64 + ((mc * 32 + hi * 8) ^ ((vrow & 7) << 3))];
          oacc[dvc] = __builtin_amdgcn_mfma_f32_16x16x32_bf16(pf, vf, oacc[dvc], 0, 0, 0);
        }
      }

      __builtin_amdgcn_s_setprio(0);
    }

    // write out (fp32), C-frag layout: row q = 4*hi+r, col dv = dvc*16+lo
#pragma unroll
    for (int dvc = 0; dvc < 4; ++dvc) {
#pragma unroll
      for (int r = 0; r < 4; ++r) {
        int nn = n0 + w * 16 + hi * 4 + r;
        if (nn < L)
          out[(size_t)(off + nn) * STRIDE + h * DDIM + dvc * 16 + lo] = oacc[dvc][r];
      }
    }
  }
}

// ---- fallback (ws too small / B>16): reg-staged fp32 queue path ----
__launch_bounds__(256)
__global__ void hstu_fb(const float* __restrict__ tq,
                        const float* __restrict__ tk,
                        const float* __restrict__ tv,
                        const int* __restrict__ offsets,
                        const int* __restrict__ pN,
                        const int* __restrict__ ncand,
                        const int* __restrict__ nctx,
                        float* __restrict__ out,
                        uint* __restrict__ ctr,
                        int Tm1, int Bb) {
  const int bhc    = Bb * HH;
  const int nitems = NORD * bhc;

  __shared__ ushort Ks[KT * DDIM];
  __shared__ ushort Vt[DDIM * KT];
  __shared__ ushort Ps[4 * 1024];
  __shared__ int s_item;

  const int tid  = threadIdx.x;
  const int w    = tid >> 6;
  const int lane = tid & 63;
  const int lo   = lane & 15;
  const int hi   = lane >> 4;
  const float invN = 1.0f / (float)pN[0];
  ushort* Pw = &Ps[w * 1024];

  for (;;) {
    __syncthreads();
    if (tid == 0) s_item = (int)atomicAdd(ctr, 1u);
    __syncthreads();
    const int item = s_item;
    if (item >= nitems) return;
    const int ord = item / bhc;
    const int rem = item - ord * bhc;
    const int b = rem / HH, h = rem - b * HH;
    const int qt = (ord == 0) ? 0 : (NORD - ord);
    const int off = offsets[b];
    const int L   = offsets[b + 1] - off;
    const int n0  = qt * QT;
    if (n0 >= L) continue;

    const int c = nctx[b];
    const int M = L - c + 1 - ncand[b];
    const int m_hi  = (n0 < c) ? L : min(n0 + QT, L);
    const int niter = (m_hi + KT - 1) / KT;

    short8 qf[2];
    {
      int qr = min(off + n0 + w * 16 + lo, Tm1);
      const float* qp = tq + (size_t)qr * STRIDE + h * DDIM + hi * 8;
      float4 qa = *(const float4*)(qp);
      float4 qb = *(const float4*)(qp + 4);
      float4 qc = *(const float4*)(qp + 32);
      float4 qd = *(const float4*)(qp + 36);
      u32x4 v0 = {pk2(qa.x, qa.y), pk2(qa.z, qa.w), pk2(qb.x, qb.y), pk2(qb.z, qb.w)};
      u32x4 v1 = {pk2(qc.x, qc.y), pk2(qc.z, qc.w), pk2(qd.x, qd.y), pk2(qd.z, qd.w)};
      qf[0] = __builtin_bit_cast(short8, v0);
      qf[1] = __builtin_bit_cast(short8, v1);
    }

    const int  n   = n0 + w * 16 + lo;
    const int  an  = min(max(n - c + 1, 0), M);
    const int  thr = (an > 0 ? an : M) + c - 1;
    const bool nok = n < L;

    f32x4 oacc[4];
#pragma unroll
    for (int i = 0; i < 4; ++i) oacc[i] = (f32x4){0.f, 0.f, 0.f, 0.f};

    for (int t = 0; t < niter; ++t) {
      const int m0 = t * KT;
      __syncthreads();
#pragma unroll
      for (int jj = 0; jj < 4; ++jj) {
        int row = (tid >> 4) + jj * 16;
        int r2  = min(off + m0 + row, Tm1);
        float4 kv = *(const float4*)(tk + (size_t)r2 * STRIDE + h * DDIM + (tid & 15) * 4);
        uint2 pk;
        pk.x = pk2(kv.x, kv.y);
        pk.y = pk2(kv.z, kv.w);
        *(uint2*)&Ks[row * 64 + (((tid & 15) * 4) ^ ((row & 7) << 3))] = pk;
      }
      {
        uint bb[8];
#pragma unroll
        for (int j = 0; j < 8; ++j) {
          int ra = min(off + m0 + w * 16 + 2 * j,     Tm1);
          int rb = min(off + m0 + w * 16 + 2 * j + 1, Tm1);
          float va = tv[(size_t)ra * STRIDE + h * DDIM + lane];
          float vb = tv[(size_t)rb * STRIDE + h * DDIM + lane];
          bb[j] = pk2(va, vb);
        }
        int s = (lane & 7) << 3;
        *(uint4*)&Vt[lane * 64 + ((w * 16)     ^ s)] = make_uint4(bb[0], bb[1], bb[2], bb[3]);
        *(uint4*)&Vt[lane * 64 + ((w * 16 + 8) ^ s)] = make_uint4(bb[4], bb[5], bb[6], bb[7]);
      }
      __syncthreads();

#pragma unroll
      for (int kc = 0; kc < 4; ++kc) {
        const int krw = kc * 16 + lo;
        const int ksw = (krw & 7) << 3;
        short8 kf0 = *(const short8*)&Ks[krw * 64 + ((hi * 8) ^ ksw)];
        short8 kf1 = *(const short8*)&Ks[krw * 64 + ((32 + hi * 8) ^ ksw)];
        f32x4 s4 = (f32x4){0.f, 0.f, 0.f, 0.f};
        s4 = __builtin_amdgcn_mfma_f32_16x16x32_bf16(kf0, qf[0], s4, 0, 0, 0);
        s4 = __builtin_amdgcn_mfma_f32_16x16x32_bf16(kf1, qf[1], s4, 0, 0, 0);
        const int mb = m0 + kc * 16 + 4 * hi;
        float pp[4];
#pragma unroll
        for (int r = 0; r < 4; ++r) {
          const int mm = mb + r;
          const bool valid = nok & ((mm < thr) | (mm == n));
          float s = valid ? s4[r] : 0.f;
          pp[r] = s * invN * __builtin_amdgcn_rcpf(1.f + __expf(-s));
        }
        const int col = kc * 16 + 4 * hi;
        *(uint2*)&Pw[lo * 64 + (col ^ ((lo & 7) << 3))] =
            make_uint2(pk2(pp[0], pp[1]), pk2(pp[2], pp[3]));
      }

#pragma unroll
      for (int mc = 0; mc < 2; ++mc) {
        short8 pf = *(const short8*)&Pw[lo * 64 + ((mc * 32 + hi * 8) ^ ((lo & 7) << 3))];
#pragma unroll
        for (int dvc = 0; dvc < 4; ++dvc) {
          const int vrow = dvc * 16 + lo;
          short8 vf = *(const short8*)&Vt[vrow * 64 + ((mc * 32 + hi * 8) ^ ((vrow & 7) << 3))];
          oacc[dvc] = __builtin_amdgcn_mfma_f32_16x16x32_bf16(pf, vf, oacc[dvc], 0, 0, 0);
        }
      }
    }

#pragma unroll
    for (int dvc = 0; dvc < 4; ++dvc) {
#pragma unroll
      for (int r = 0; r < 4; ++r) {
        int nn = n0 + w * 16 + hi * 4 + r;
        if (nn < L)
          out[(size_t)(off + nn) * STRIDE + h * DDIM + dvc * 16 + lo] = oacc[dvc][r];
      }
    }
  }
}

extern "C" void kernel_launch(void* const* d_in, const int* in_sizes, int n_in,
                              void* d_out, int out_size, void* d_ws, size_t ws_size,
                              hipStream_t stream) {
  const float* tq      = (const float*)d_in[0];
  const float* tk      = (const float*)d_in[1];
  const float* tv      = (const float*)d_in[2];
  const int*   offsets = (const int*)d_in[3];
  const int*   pN      = (const int*)d_in[4];
  const int*   ncand   = (const int*)d_in[5];
  const int*   nctx    = (const int*)d_in[6];
  float*       out     = (float*)d_out;

  const int B = in_sizes[3] - 1;
  const int T = in_sizes[0] / STRIDE;

  uint*   ctr   = (uint*)d_ws;
  ushort* tiles = (ushort*)((char*)d_ws + 256);
  const size_t need = 256 + (size_t)B * NORD * HH * TILE_HW * sizeof(ushort);

  dim3 block(256);

  if (ws_size >= need && B <= 16) {
    dim3 tgrid(NORD, HH, B);
    build_tiles<<<tgrid, block, 0, stream>>>(tk, tv, tiles, offsets, pN);
    hstu_s<<<NBLK, block, 0, stream>>>(tq, tiles, offsets, ncand, nctx, out,
                                       T - 1, B);
  } else {
    zero_ctr<<<1, 1, 0, stream>>>(ctr);
    hstu_fb<<<NBLK, block, 0, stream>>>(tq, tk, tv, offsets, pN, ncand,
                                        nctx, out, ctr, T - 1, B);
  }
}